// Round 7
// baseline (318.483 us; speedup 1.0000x reference)
//
#include <hip/hip_runtime.h>
#include <hip/hip_bf16.h>
#include <stdint.h>
#include <stddef.h>

using bf16 = __hip_bfloat16;

typedef __attribute__((ext_vector_type(4))) float f32x4;
typedef __attribute__((ext_vector_type(8))) short bf16x8;
typedef __attribute__((ext_vector_type(4))) unsigned short u16x4;

#define K_DIM 4096
#define M_ROWS 8192
#define BM 256
#define BN 256
#define BK 64
#define NT (K_DIM / BK)      // 64 K-tiles
#define MT2 (M_ROWS / BM)    // 32
#define NT2 (K_DIM / BN)     // 16

template<int M> struct MC { static constexpr int value = M; };

// ---------------------------------------------------------------------------
// Kernel 1: f32 -> bf16 conversion (vectorized, grid-stride)
// ---------------------------------------------------------------------------
__global__ void conv_bf16(const float* __restrict__ in, bf16* __restrict__ outb, int n4) {
  int idx = blockIdx.x * blockDim.x + threadIdx.x;
  int stride = gridDim.x * blockDim.x;
  for (int k = idx; k < n4; k += stride) {
    f32x4 v = ((const f32x4*)in)[k];
    bf16 tmp[4];
    tmp[0] = __float2bfloat16(v.x);
    tmp[1] = __float2bfloat16(v.y);
    tmp[2] = __float2bfloat16(v.z);
    tmp[3] = __float2bfloat16(v.w);
    ((u16x4*)outb)[k] = *(const u16x4*)tmp;
  }
}

// ---------------------------------------------------------------------------
// Kernel 2: build G^T in bf16 (verified round 1).
// ---------------------------------------------------------------------------
__global__ void build_gt(const float* __restrict__ core0, const float* __restrict__ core1,
                         bf16* __restrict__ GT) {
  int j = blockIdx.x >> 6;
  int i = blockIdx.x & 63;
  __shared__ float c0s[64][16];
  __shared__ float c1s[64][16];
  int t = threadIdx.x;
#pragma unroll
  for (int rep = 0; rep < 4; ++rep) {
    int idx = rep * 256 + t;
    int row = idx >> 4;
    int b = idx & 15;
    size_t base = ((size_t)(j * 64 + row) * 64 + i) * 16 + b;
    c1s[row][b] = core1[base];
    c0s[row][b] = core0[base];
  }
  __syncthreads();
  int x = t & 63;
  int ys = t >> 6;
  float r1[16];
#pragma unroll
  for (int b = 0; b < 16; ++b) r1[b] = c1s[x][b];
#pragma unroll
  for (int yy = 0; yy < 16; ++yy) {
    int y = ys * 16 + yy;
    float acc = 0.f;
#pragma unroll
    for (int b = 0; b < 16; ++b) acc += r1[b] * c0s[y][b];
    GT[((size_t)(y * 64 + i) << 12) + (size_t)(j * 64 + x)] = __float2bfloat16(acc);
  }
}

// ---------------------------------------------------------------------------
// Kernel 3: R3 skeleton (4 phases/K-tile, 2 barriers/phase, vmcnt(4)/tile)
// + fragment reads pipelined ONE PHASE AHEAD (split sets af0/af1/bfr) so the
// pre-MFMA lgkm waits are counted and stall-free.
// ---------------------------------------------------------------------------
__device__ __forceinline__ void gload_lds16(const bf16* g, bf16* l) {
  __builtin_amdgcn_global_load_lds(
      (const __attribute__((address_space(1))) unsigned int*)(g),
      (__attribute__((address_space(3))) unsigned int*)(l),
      16, 0, 0);
}

// read one A half (MH selected via base offset) into a private set
__device__ __forceinline__ void read_ah(bf16x8 (&af)[4][2], const bf16* As,
                                        int abaseMH, int swk0, int swk1) {
#pragma unroll
  for (int mi = 0; mi < 4; ++mi) {
    int off = abaseMH + mi * 1024;   // 16 rows * 64 elem
    af[mi][0] = *(const bf16x8*)&As[off + swk0];
    af[mi][1] = *(const bf16x8*)&As[off + swk1];
  }
}

template<int NH>
__device__ __forceinline__ void read_b(bf16x8 (&bfr)[4][2], const bf16* Bs,
                                       int bbase, int swk0, int swk1) {
#pragma unroll
  for (int ni = 0; ni < 2; ++ni) {
    int off = bbase + (NH * 2 + ni) * 1024;
    bfr[NH * 2 + ni][0] = *(const bf16x8*)&Bs[off + swk0];
    bfr[NH * 2 + ni][1] = *(const bf16x8*)&Bs[off + swk1];
  }
}

template<int MH, int NH>
__device__ __forceinline__ void mfma_quad(f32x4 (&acc)[8][4], const bf16x8 (&af)[4][2],
                                          const bf16x8 (&bfr)[4][2]) {
#pragma unroll
  for (int mi = 0; mi < 4; ++mi)
#pragma unroll
    for (int ni = 0; ni < 2; ++ni)
#pragma unroll
      for (int kk = 0; kk < 2; ++kk)
        acc[MH * 4 + mi][NH * 2 + ni] = __builtin_amdgcn_mfma_f32_16x16x32_bf16(
            af[mi][kk], bfr[NH * 2 + ni][kk], acc[MH * 4 + mi][NH * 2 + ni], 0, 0, 0);
}

#define BARRIER() __builtin_amdgcn_s_barrier()
#define SP1() __builtin_amdgcn_s_setprio(1)
#define SP0() __builtin_amdgcn_s_setprio(0)
#define VMCNT4() asm volatile("s_waitcnt vmcnt(4)" ::: "memory")
#define VMCNT0() asm volatile("s_waitcnt vmcnt(0)" ::: "memory")

__global__ __launch_bounds__(512, 2)
void gemm_xg(const bf16* __restrict__ Xb, const bf16* __restrict__ GT,
             const float* __restrict__ bias, float* __restrict__ out) {
  __shared__ bf16 As[2][BM * BK];   // 2 x 32 KiB
  __shared__ bf16 Bs[2][BN * BK];   // 2 x 32 KiB

  // XCD-aware swizzle: nwg = 512, divisible by 8
  int bid = blockIdx.x;
  int sb = (bid & 7) * (MT2 * NT2 / 8) + (bid >> 3);
  int bm = sb >> 4;
  int bn = sb & 15;

  int t = threadIdx.x;
  int lane = t & 63;
  int wid = t >> 6;

  // ---- staging addressing (linear LDS dest, inverse-swizzled global src) ----
  int srow = t >> 3;                    // 0..63
  int scol = t & 7;                     // 16B slot
  int sxor = scol ^ (srow & 7);         // pre-swizzled global slot
  const bf16* gA0 = Xb + ((size_t)(bm * BM + srow) * K_DIM) + sxor * 8;
  const bf16* gB0 = GT + ((size_t)(bn * BN + srow) * K_DIM) + sxor * 8;
  int lbase = srow * BK + scol * 8;

  auto sA = [&](int buf, int h, int kt) {
    const bf16* g = gA0 + (size_t)(h * 128) * K_DIM + (size_t)kt * BK;
    bf16* l = &As[buf][h * 128 * BK + lbase];
    gload_lds16(g, l);
    gload_lds16(g + (size_t)64 * K_DIM, l + 64 * BK);
  };
  auto sB = [&](int buf, int h, int kt) {
    const bf16* g = gB0 + (size_t)(h * 128) * K_DIM + (size_t)kt * BK;
    bf16* l = &Bs[buf][h * 128 * BK + lbase];
    gload_lds16(g, l);
    gload_lds16(g + (size_t)64 * K_DIM, l + 64 * BK);
  };

  // ---- fragment addressing (swizzled ds_read) ----
  int wm = wid >> 2;        // 0..1
  int wn = wid & 3;         // 0..3
  int lr = lane & 15;
  int g4 = lane >> 4;
  int x7 = lr & 7;
  int swk0 = ((g4 ^ x7) << 3);
  int swk1 = (((4 + g4) ^ x7) << 3);
  int abase = (wm * 128 + lr) * BK;     // MH offset = + MH*4096
  int bbase = (wn * 64 + lr) * BK;

  f32x4 acc[8][4] = {};
  bf16x8 af0[4][2];   // A-MH0 of current tile (read one phase before Q00)
  bf16x8 af1[4][2];   // A-MH1 of current tile (read at ph1)
  bf16x8 bfr[4][2];   // B NH0+NH1 of current tile

  const bf16* A0 = &As[0][0];
  const bf16* B0 = &Bs[0][0];
  const bf16* A1 = &As[1][0];
  const bf16* B1 = &Bs[1][0];

  // ---- prologue: stage tile0 + B(1); drain tile0 (keep B(1)); pre-read ----
  sB(0, 0, 0); sB(0, 1, 0);
  sA(0, 0, 0); sA(0, 1, 0);
  sB(1, 0, 1); sB(1, 1, 1);
  VMCNT4();
  BARRIER();
  read_ah(af0, A0, abase, swk0, swk1);        // A-MH0(0)
  read_b<0>(bfr, B0, bbase, swk0, swk1);      // B-NH0(0)

  // ---- per-tile: 4 phases; reads one phase ahead of their MFMA use ----
  // MODE: 0=steady, 1=t==NT-2 (skip B stages, drain-0), 2=t==NT-1 (last)
  auto tile = [&](int kt, const bf16* Ac, const bf16* Bc,
                  const bf16* Ao, const bf16* Bo,
                  int bufAn, int bufBn, auto modec) {
    constexpr int MODE = decltype(modec)::value;

    // ph0: Q00 (af0, bfr-NH0 pre-read last phase); read B-NH1(t); stage A(t+1)h0
    read_b<1>(bfr, Bc, bbase, swk0, swk1);
    if (MODE < 2) sA(bufAn, 0, kt + 1);
    BARRIER(); SP1(); mfma_quad<0, 0>(acc, af0, bfr); SP0(); BARRIER();

    // ph1: Q01 (af0, bfr-NH1); read A-MH1(t); stage A(t+1)h1
    read_ah(af1, Ac, abase + 4096, swk0, swk1);
    if (MODE < 2) sA(bufAn, 1, kt + 1);
    BARRIER(); SP1(); mfma_quad<0, 1>(acc, af0, bfr); SP0(); BARRIER();

    // ph2: Q10 (af1, bfr-NH0); stage B(t+2)h0
    if (MODE == 0) sB(bufBn, 0, kt + 2);
    BARRIER(); SP1(); mfma_quad<1, 0>(acc, af1, bfr); SP0(); BARRIER();

    // ph3: Q11 (af1, bfr-NH1); stage B(t+2)h1; vmcnt; barrier; then next-tile
    // Q00 operands (A-MH0(t+1), B-NH0(t+1)) — safe: vmcnt->barrier->read.
    if (MODE == 0) sB(bufBn, 1, kt + 2);
    if (MODE == 0) { VMCNT4(); } else if (MODE == 1) { VMCNT0(); }
    BARRIER();
    if (MODE < 2) {
      read_ah(af0, Ao, abase, swk0, swk1);
      read_b<0>(bfr, Bo, bbase, swk0, swk1);
    }
    SP1(); mfma_quad<1, 1>(acc, af1, bfr); SP0(); BARRIER();
  };

#pragma unroll 1
  for (int i = 0; i < NT / 2 - 1; ++i) {
    tile(2 * i,     A0, B0, A1, B1, 1, 0, MC<0>{});
    tile(2 * i + 1, A1, B1, A0, B0, 0, 1, MC<0>{});
  }
  tile(NT - 2, A0, B0, A1, B1, 1, 0, MC<1>{});
  tile(NT - 1, A1, B1, A0, B0, 0, 1, MC<2>{});

  // ---- epilogue: C/D layout col = lane&15, row = (lane>>4)*4 + r ----
  int colbase = bn * BN + wn * 64 + lr;
  int rowbase = bm * BM + wm * 128 + g4 * 4;
#pragma unroll
  for (int ni = 0; ni < 4; ++ni) {
    int col = colbase + ni * 16;
    float bv = bias[col];
#pragma unroll
    for (int mi = 0; mi < 8; ++mi) {
#pragma unroll
      for (int r = 0; r < 4; ++r) {
        int row = rowbase + mi * 16 + r;
        out[(size_t)row * K_DIM + col] = acc[mi][ni][r] + bv;
      }
    }
  }
}

// ---------------------------------------------------------------------------
extern "C" void kernel_launch(void* const* d_in, const int* in_sizes, int n_in,
                              void* d_out, int out_size, void* d_ws, size_t ws_size,
                              hipStream_t stream) {
  const float* x     = (const float*)d_in[0];
  const float* core0 = (const float*)d_in[1];
  const float* core1 = (const float*)d_in[2];
  const float* bias  = (const float*)d_in[3];
  float* out = (float*)d_out;

  bf16* Xb = (bf16*)d_ws;
  bf16* GT = (bf16*)((char*)d_ws + (size_t)M_ROWS * K_DIM * sizeof(bf16));

  conv_bf16<<<2048, 256, 0, stream>>>(x, Xb, (M_ROWS * K_DIM) / 4);
  build_gt<<<4096, 256, 0, stream>>>(core0, core1, GT);
  gemm_xg<<<MT2 * NT2, 512, 0, stream>>>(Xb, GT, bias, out);
}

// Round 8
// 287.672 us; speedup vs baseline: 1.1071x; 1.1071x over previous
//
#include <hip/hip_runtime.h>
#include <hip/hip_bf16.h>
#include <stdint.h>
#include <stddef.h>

using bf16 = __hip_bfloat16;

typedef __attribute__((ext_vector_type(4))) float f32x4;
typedef __attribute__((ext_vector_type(8))) short bf16x8;
typedef __attribute__((ext_vector_type(4))) unsigned short u16x4;

#define K_DIM 4096
#define M_ROWS 8192
#define BM 256
#define BN 256
#define BK 64
#define NT (K_DIM / BK)      // 64 K-tiles
#define NITER (NT / 2)       // 32 iterations, 2 K-tiles each
#define MT2 (M_ROWS / BM)    // 32
#define NT2 (K_DIM / BN)     // 16

template<bool B> struct BC { static constexpr bool value = B; };

// ---------------------------------------------------------------------------
// Kernel 1: f32 -> bf16 conversion (vectorized, grid-stride)
// ---------------------------------------------------------------------------
__global__ void conv_bf16(const float* __restrict__ in, bf16* __restrict__ outb, int n4) {
  int idx = blockIdx.x * blockDim.x + threadIdx.x;
  int stride = gridDim.x * blockDim.x;
  for (int k = idx; k < n4; k += stride) {
    f32x4 v = ((const f32x4*)in)[k];
    bf16 tmp[4];
    tmp[0] = __float2bfloat16(v.x);
    tmp[1] = __float2bfloat16(v.y);
    tmp[2] = __float2bfloat16(v.z);
    tmp[3] = __float2bfloat16(v.w);
    ((u16x4*)outb)[k] = *(const u16x4*)tmp;
  }
}

// ---------------------------------------------------------------------------
// Kernel 2: build G^T in bf16 (verified round 1).
// ---------------------------------------------------------------------------
__global__ void build_gt(const float* __restrict__ core0, const float* __restrict__ core1,
                         bf16* __restrict__ GT) {
  int j = blockIdx.x >> 6;
  int i = blockIdx.x & 63;
  __shared__ float c0s[64][16];
  __shared__ float c1s[64][16];
  int t = threadIdx.x;
#pragma unroll
  for (int rep = 0; rep < 4; ++rep) {
    int idx = rep * 256 + t;
    int row = idx >> 4;
    int b = idx & 15;
    size_t base = ((size_t)(j * 64 + row) * 64 + i) * 16 + b;
    c1s[row][b] = core1[base];
    c0s[row][b] = core0[base];
  }
  __syncthreads();
  int x = t & 63;
  int ys = t >> 6;
  float r1[16];
#pragma unroll
  for (int b = 0; b < 16; ++b) r1[b] = c1s[x][b];
#pragma unroll
  for (int yy = 0; yy < 16; ++yy) {
    int y = ys * 16 + yy;
    float acc = 0.f;
#pragma unroll
    for (int b = 0; b < 16; ++b) acc += r1[b] * c0s[y][b];
    GT[((size_t)(y * 64 + i) << 12) + (size_t)(j * 64 + x)] = __float2bfloat16(acc);
  }
}

// ---------------------------------------------------------------------------
// Kernel 3: R3's 8-phase skeleton (verified fastest) with m201-exact sync
// mechanics: asm s_barrier (invisible to the memory legalizer -> no implicit
// vmcnt(0)/lgkmcnt(0) drains), explicit lgkmcnt(0)+sched_barrier AFTER the
// pre-MFMA barrier, counted vmcnt(4) only at tile entries.
// ---------------------------------------------------------------------------
__device__ __forceinline__ void gload_lds16(const bf16* g, bf16* l) {
  __builtin_amdgcn_global_load_lds(
      (const __attribute__((address_space(1))) unsigned int*)(g),
      (__attribute__((address_space(3))) unsigned int*)(l),
      16, 0, 0);
}

template<int MH>
__device__ __forceinline__ void read_a(bf16x8 (&af)[4][2], const bf16* As,
                                       int abase, int swk0, int swk1) {
#pragma unroll
  for (int mi = 0; mi < 4; ++mi) {
    int off = abase + (MH * 4 + mi) * 1024;   // 16 rows * 64 elem
    af[mi][0] = *(const bf16x8*)&As[off + swk0];
    af[mi][1] = *(const bf16x8*)&As[off + swk1];
  }
}

template<int NH>
__device__ __forceinline__ void read_b(bf16x8 (&bfr)[4][2], const bf16* Bs,
                                       int bbase, int swk0, int swk1) {
#pragma unroll
  for (int ni = 0; ni < 2; ++ni) {
    int off = bbase + (NH * 2 + ni) * 1024;
    bfr[NH * 2 + ni][0] = *(const bf16x8*)&Bs[off + swk0];
    bfr[NH * 2 + ni][1] = *(const bf16x8*)&Bs[off + swk1];
  }
}

template<int MH, int NH>
__device__ __forceinline__ void mfma_quad(f32x4 (&acc)[8][4], const bf16x8 (&af)[4][2],
                                          const bf16x8 (&bfr)[4][2]) {
#pragma unroll
  for (int mi = 0; mi < 4; ++mi)
#pragma unroll
    for (int ni = 0; ni < 2; ++ni)
#pragma unroll
      for (int kk = 0; kk < 2; ++kk)
        acc[MH * 4 + mi][NH * 2 + ni] = __builtin_amdgcn_mfma_f32_16x16x32_bf16(
            af[mi][kk], bfr[NH * 2 + ni][kk], acc[MH * 4 + mi][NH * 2 + ni], 0, 0, 0);
}

#define BARRIER() asm volatile("s_barrier" ::: "memory")
#define LGKM0_FENCE() do { \
    asm volatile("s_waitcnt lgkmcnt(0)" ::: "memory"); \
    __builtin_amdgcn_sched_barrier(0); \
  } while (0)
#define SP1() __builtin_amdgcn_s_setprio(1)
#define SP0() __builtin_amdgcn_s_setprio(0)
#define VMCNT4() asm volatile("s_waitcnt vmcnt(4)" ::: "memory")
#define VMCNT0() asm volatile("s_waitcnt vmcnt(0)" ::: "memory")

__global__ __launch_bounds__(512, 2)
void gemm_xg(const bf16* __restrict__ Xb, const bf16* __restrict__ GT,
             const float* __restrict__ bias, float* __restrict__ out) {
  __shared__ bf16 As[2][BM * BK];   // 2 x 32 KiB
  __shared__ bf16 Bs[2][BN * BK];   // 2 x 32 KiB

  // XCD-aware swizzle: nwg = 512, divisible by 8
  int bid = blockIdx.x;
  int sb = (bid & 7) * (MT2 * NT2 / 8) + (bid >> 3);
  int bm = sb >> 4;
  int bn = sb & 15;

  int t = threadIdx.x;
  int lane = t & 63;
  int wid = t >> 6;

  // ---- staging addressing (linear LDS dest, inverse-swizzled global src) ----
  int srow = t >> 3;                    // 0..63
  int scol = t & 7;                     // 16B slot
  int sxor = scol ^ (srow & 7);         // pre-swizzled global slot
  const bf16* gA0 = Xb + ((size_t)(bm * BM + srow) * K_DIM) + sxor * 8;
  const bf16* gB0 = GT + ((size_t)(bn * BN + srow) * K_DIM) + sxor * 8;
  int lbase = srow * BK + scol * 8;

  auto sA = [&](int buf, int h, int kt) {
    const bf16* g = gA0 + (size_t)(h * 128) * K_DIM + (size_t)kt * BK;
    bf16* l = &As[buf][h * 128 * BK + lbase];
    gload_lds16(g, l);
    gload_lds16(g + (size_t)64 * K_DIM, l + 64 * BK);
  };
  auto sB = [&](int buf, int h, int kt) {
    const bf16* g = gB0 + (size_t)(h * 128) * K_DIM + (size_t)kt * BK;
    bf16* l = &Bs[buf][h * 128 * BK + lbase];
    gload_lds16(g, l);
    gload_lds16(g + (size_t)64 * K_DIM, l + 64 * BK);
  };

  // ---- fragment addressing (swizzled ds_read) ----
  int wm = wid >> 2;        // 0..1
  int wn = wid & 3;         // 0..3
  int lr = lane & 15;
  int g4 = lane >> 4;
  int x7 = lr & 7;
  int swk0 = ((g4 ^ x7) << 3);
  int swk1 = (((4 + g4) ^ x7) << 3);
  int abase = (wm * 128 + lr) * BK;
  int bbase = (wn * 64 + lr) * BK;

  f32x4 acc[8][4] = {};
  bf16x8 af[4][2];
  bf16x8 bfr[4][2];

  const bf16* A0 = &As[0][0];
  const bf16* B0 = &Bs[0][0];
  const bf16* A1 = &As[1][0];
  const bf16* B1 = &Bs[1][0];

  // ---- prologue: tile0 full + tile1 B-halves; counted drain (keep B(1)) ----
  sB(0, 0, 0); sB(0, 1, 0);
  sA(0, 0, 0); sA(0, 1, 0);
  sB(1, 0, 1); sB(1, 1, 1);
  VMCNT4();
  BARRIER();

  // ---- main loop: iteration i = tiles t0=2i (buf0), t1=2i+1 (buf1) ----
  auto run_iter = [&](int i, auto lastc) {
    constexpr bool LAST = decltype(lastc)::value;
    const int t1 = 2 * i + 1, t2 = 2 * i + 2, t3 = 2 * i + 3;

    // ph0: Q(0,0) of t0
    VMCNT4();                                    // drains B(t0),A(t0); keeps B(t1)
    read_a<0>(af, A0, abase, swk0, swk1);
    read_b<0>(bfr, B0, bbase, swk0, swk1);
    sA(1, 0, t1);
    BARRIER(); LGKM0_FENCE();
    SP1(); mfma_quad<0, 0>(acc, af, bfr); SP0(); BARRIER();

    // ph1: Q(0,1) of t0
    read_b<1>(bfr, B0, bbase, swk0, swk1);
    sA(1, 1, t1);
    BARRIER(); LGKM0_FENCE();
    SP1(); mfma_quad<0, 1>(acc, af, bfr); SP0(); BARRIER();

    // ph2: Q(1,0) of t0
    read_a<1>(af, A0, abase, swk0, swk1);
    if (!LAST) sB(0, 0, t2);
    BARRIER(); LGKM0_FENCE();
    SP1(); mfma_quad<1, 0>(acc, af, bfr); SP0(); BARRIER();

    // ph3: Q(1,1) of t0
    if (!LAST) sB(0, 1, t2);
    BARRIER(); LGKM0_FENCE();
    SP1(); mfma_quad<1, 1>(acc, af, bfr); SP0(); BARRIER();

    // ph4: Q(0,0) of t1
    if (!LAST) { VMCNT4(); } else { VMCNT0(); }  // drains B(t1),A(t1); keeps B(t2)
    read_a<0>(af, A1, abase, swk0, swk1);
    read_b<0>(bfr, B1, bbase, swk0, swk1);
    if (!LAST) sA(0, 0, t2);
    BARRIER(); LGKM0_FENCE();
    SP1(); mfma_quad<0, 0>(acc, af, bfr); SP0(); BARRIER();

    // ph5: Q(0,1) of t1
    read_b<1>(bfr, B1, bbase, swk0, swk1);
    if (!LAST) sA(0, 1, t2);
    BARRIER(); LGKM0_FENCE();
    SP1(); mfma_quad<0, 1>(acc, af, bfr); SP0(); BARRIER();

    // ph6: Q(1,0) of t1
    read_a<1>(af, A1, abase, swk0, swk1);
    if (!LAST) sB(1, 0, t3);
    BARRIER(); LGKM0_FENCE();
    SP1(); mfma_quad<1, 0>(acc, af, bfr); SP0(); BARRIER();

    // ph7: Q(1,1) of t1
    if (!LAST) sB(1, 1, t3);
    BARRIER(); LGKM0_FENCE();
    SP1(); mfma_quad<1, 1>(acc, af, bfr); SP0(); BARRIER();
  };

#pragma unroll 1
  for (int i = 0; i < NITER - 1; ++i) run_iter(i, BC<false>{});
  run_iter(NITER - 1, BC<true>{});

  // ---- epilogue: C/D layout col = lane&15, row = (lane>>4)*4 + r ----
  int colbase = bn * BN + wn * 64 + lr;
  int rowbase = bm * BM + wm * 128 + g4 * 4;
#pragma unroll
  for (int ni = 0; ni < 4; ++ni) {
    int col = colbase + ni * 16;
    float bv = bias[col];
#pragma unroll
    for (int mi = 0; mi < 8; ++mi) {
#pragma unroll
      for (int r = 0; r < 4; ++r) {
        int row = rowbase + mi * 16 + r;
        out[(size_t)row * K_DIM + col] = acc[mi][ni][r] + bv;
      }
    }
  }
}

// ---------------------------------------------------------------------------
extern "C" void kernel_launch(void* const* d_in, const int* in_sizes, int n_in,
                              void* d_out, int out_size, void* d_ws, size_t ws_size,
                              hipStream_t stream) {
  const float* x     = (const float*)d_in[0];
  const float* core0 = (const float*)d_in[1];
  const float* core1 = (const float*)d_in[2];
  const float* bias  = (const float*)d_in[3];
  float* out = (float*)d_out;

  bf16* Xb = (bf16*)d_ws;
  bf16* GT = (bf16*)((char*)d_ws + (size_t)M_ROWS * K_DIM * sizeof(bf16));

  conv_bf16<<<2048, 256, 0, stream>>>(x, Xb, (M_ROWS * K_DIM) / 4);
  build_gt<<<4096, 256, 0, stream>>>(core0, core1, GT);
  gemm_xg<<<MT2 * NT2, 512, 0, stream>>>(Xb, GT, bias, out);
}